// Round 1
// baseline (4928.237 us; speedup 1.0000x reference)
//
#include <hip/hip_runtime.h>
#include <hip/hip_bf16.h>

// Problem constants
#define B_  4
#define N_  16
#define T_  2048
#define F_  512
#define NC_ 43
constexpr float LN_EPS = 1e-5f;

constexpr int EMB1_N = NC_ * F_;            // 22016
constexpr int WBOX_N = F_ * 4;              // 2048
constexpr int W2T_N  = F_ * F_;             // 262144
constexpr int WM3_N  = N_ * F_ * F_;        // 4194304 (k = n*F+c, f)
constexpr long long H2_N = (long long)B_ * T_ * N_ * F_;  // 67108864

// ---------------------------------------------------------------------------
// K0a: emb1[k][f] = sum_c emb_table[k][c] * W1[f][c]          (c in [0,F))
//      wbox[f][q] = sum_c W1[f][F+c] * W_lin[c][q]
//      w2t[c][f]  = W2[f][c]
// ---------------------------------------------------------------------------
__global__ __launch_bounds__(256) void precompute_small(
    const float* __restrict__ emb_table, const float* __restrict__ W1,
    const float* __restrict__ W_lin, const float* __restrict__ W2,
    float* __restrict__ emb1, float* __restrict__ wbox, float* __restrict__ w2t)
{
  int idx = blockIdx.x * 256 + threadIdx.x;
  if (idx < EMB1_N) {
    int k = idx >> 9, f = idx & 511;
    float s = 0.f;
    for (int c = 0; c < F_; ++c) s = fmaf(emb_table[k * F_ + c], W1[f * (2 * F_) + c], s);
    emb1[idx] = s;
  } else if (idx < EMB1_N + WBOX_N) {
    int t2 = idx - EMB1_N;
    int f = t2 >> 2, q = t2 & 3;
    float s = 0.f;
    for (int c = 0; c < F_; ++c) s = fmaf(W1[f * (2 * F_) + F_ + c], W_lin[c * 4 + q], s);
    wbox[t2] = s;
  } else if (idx < EMB1_N + WBOX_N + W2T_N) {
    int t3 = idx - (EMB1_N + WBOX_N);
    int c = t3 >> 9, f = t3 & 511;
    w2t[t3] = W2[f * F_ + c];  // w2t[c][f]
  }
}

// ---------------------------------------------------------------------------
// K0b: wm3[k][f] (bf16), k = n*F + c  ->  Wm[f][c][n]
// ---------------------------------------------------------------------------
__global__ __launch_bounds__(256) void precompute_wm3(
    const float* __restrict__ Wm, __hip_bfloat16* __restrict__ wm3)
{
  int idx = blockIdx.x * 256 + threadIdx.x;  // idx = k*512 + f
  if (idx < WM3_N) {
    int f = idx & 511;
    int k = idx >> 9;
    int n = k >> 9, c = k & 511;
    wm3[idx] = __float2bfloat16(Wm[(f * F_ + c) * N_ + n]);
  }
}

// ---------------------------------------------------------------------------
// K12: per pixel p=(b,t):
//   node1[j][f] = emb1[cls[j]][f] + sum_q bbox[j][q] * wbox[f][q]
//   h1 = relu(em @ node1); node2 = h1 @ W2^T; h2 = relu(em @ node2) -> global bf16
// ---------------------------------------------------------------------------
__global__ __launch_bounds__(256) void k12(
    const float* __restrict__ bbox, const int* __restrict__ cls,
    const float* __restrict__ edge, const float* __restrict__ emb1,
    const float* __restrict__ wbox, const float* __restrict__ w2t,
    __hip_bfloat16* __restrict__ h2)
{
  __shared__ __align__(16) float em_s[256];
  __shared__ __align__(16) float bufA[N_ * F_];
  __shared__ __align__(16) float bufB[N_ * F_];
  __shared__ int   cls_s[N_];
  __shared__ float bb_s[N_ * 4];

  const int p = blockIdx.x;
  const int b = p >> 11;         // T=2048
  const int t = p & 2047;
  const int tid = threadIdx.x;

  {
    int i = tid >> 4, j = tid & 15;
    em_s[tid] = edge[(((b * N_ + i) * N_ + j) * T_) + t];
  }
  if (tid < N_) cls_s[tid] = cls[(b * N_ + tid) * T_ + t];
  if (tid < N_ * 4) {
    int j = tid >> 2, q = tid & 3;
    bb_s[tid] = bbox[(((b * N_ + j) * 4 + q) * T_) + t];
  }
  __syncthreads();

  // S1: node1 -> bufA
  const float4* wb4 = (const float4*)wbox;
  for (int idx = tid; idx < N_ * F_; idx += 256) {
    int j = idx >> 9, f = idx & 511;
    float4 wb = wb4[f];
    float v = emb1[cls_s[j] * F_ + f];
    v = fmaf(bb_s[j * 4 + 0], wb.x, v);
    v = fmaf(bb_s[j * 4 + 1], wb.y, v);
    v = fmaf(bb_s[j * 4 + 2], wb.z, v);
    v = fmaf(bb_s[j * 4 + 3], wb.w, v);
    bufA[idx] = v;
  }
  __syncthreads();

  // S2: h1 = relu(em @ node1) -> bufB
  for (int idx = tid; idx < N_ * F_; idx += 256) {
    int i = idx >> 9, f = idx & 511;
    float s = 0.f;
#pragma unroll
    for (int j = 0; j < N_; ++j) s = fmaf(em_s[i * 16 + j], bufA[j * F_ + f], s);
    bufB[idx] = fmaxf(s, 0.f);
  }
  __syncthreads();

  // S3: node2[j][f] = sum_c h1[j][c] * W2[f][c]  (via w2t[c][f]) -> bufA
  {
    const int f0 = tid, f1 = tid + 256;
    float acc0[N_], acc1[N_];
#pragma unroll
    for (int j = 0; j < N_; ++j) { acc0[j] = 0.f; acc1[j] = 0.f; }
    for (int c = 0; c < F_; c += 2) {
      float w00 = w2t[c * F_ + f0], w01 = w2t[c * F_ + f1];
      float w10 = w2t[(c + 1) * F_ + f0], w11 = w2t[(c + 1) * F_ + f1];
#pragma unroll
      for (int j = 0; j < N_; ++j) {
        float2 a = *(const float2*)&bufB[j * F_ + c];
        acc0[j] = fmaf(a.x, w00, acc0[j]);
        acc0[j] = fmaf(a.y, w10, acc0[j]);
        acc1[j] = fmaf(a.x, w01, acc1[j]);
        acc1[j] = fmaf(a.y, w11, acc1[j]);
      }
    }
#pragma unroll
    for (int j = 0; j < N_; ++j) {
      bufA[j * F_ + f0] = acc0[j];
      bufA[j * F_ + f1] = acc1[j];
    }
  }
  __syncthreads();

  // S4: h2 = relu(em @ node2) -> global bf16, layout h2[p][n*F + c]
  long long base = (long long)p * (N_ * F_);
  for (int idx = tid; idx < N_ * F_; idx += 256) {
    int i = idx >> 9, f = idx & 511;
    float s = 0.f;
#pragma unroll
    for (int j = 0; j < N_; ++j) s = fmaf(em_s[i * 16 + j], bufA[j * F_ + f], s);
    h2[base + idx] = __float2bfloat16(fmaxf(s, 0.f));
  }
}

// ---------------------------------------------------------------------------
// K3: feat[m][f] = sum_k h2[m][k] * wm3[k][f]   (M-tile = 16 pixels/block)
//     then LayerNorm over f, store out[b][f][t]
// ---------------------------------------------------------------------------
#define SA_STRIDE 514  // even, not multiple of 32: avoids LN-phase bank conflicts
__global__ __launch_bounds__(256) void k3(
    const __hip_bfloat16* __restrict__ h2, const __hip_bfloat16* __restrict__ wm3,
    const float* __restrict__ lnw, const float* __restrict__ lnb,
    float* __restrict__ out)
{
  __shared__ __align__(16) float sA[16 * SA_STRIDE];  // A-tile, then feat
  __shared__ float red[512];
  __shared__ float smu[16], srstd[16];

  const int tid = threadIdx.x;
  const int p0 = blockIdx.x * 16;
  const int b = p0 >> 11;
  const int t0 = p0 & 2047;
  const int f0 = tid, f1 = tid + 256;

  float acc0[16], acc1[16];
#pragma unroll
  for (int j = 0; j < 16; ++j) { acc0[j] = 0.f; acc1[j] = 0.f; }

  for (int kc = 0; kc < N_ * F_; kc += 512) {
    __syncthreads();
    for (int idx = tid; idx < 16 * 512; idx += 256) {
      int r = idx >> 9, k = idx & 511;
      sA[r * SA_STRIDE + k] = __bfloat162float(h2[(long long)(p0 + r) * (N_ * F_) + kc + k]);
    }
    __syncthreads();
    for (int k = 0; k < 512; k += 2) {
      float b00 = __bfloat162float(wm3[(long long)(kc + k) * F_ + f0]);
      float b01 = __bfloat162float(wm3[(long long)(kc + k) * F_ + f1]);
      float b10 = __bfloat162float(wm3[(long long)(kc + k + 1) * F_ + f0]);
      float b11 = __bfloat162float(wm3[(long long)(kc + k + 1) * F_ + f1]);
#pragma unroll
      for (int j = 0; j < 16; ++j) {
        float2 a = *(const float2*)&sA[j * SA_STRIDE + k];
        acc0[j] = fmaf(a.x, b00, acc0[j]);
        acc0[j] = fmaf(a.y, b10, acc0[j]);
        acc1[j] = fmaf(a.x, b01, acc1[j]);
        acc1[j] = fmaf(a.y, b11, acc1[j]);
      }
    }
  }
  __syncthreads();

  // feat -> sA (padded stride)
#pragma unroll
  for (int j = 0; j < 16; ++j) {
    sA[j * SA_STRIDE + f0] = acc0[j];
    sA[j * SA_STRIDE + f1] = acc1[j];
  }
  __syncthreads();

  // per-row mean/var
  {
    int r = tid >> 4, s = tid & 15;
    float sum = 0.f, sq = 0.f;
    for (int q = s; q < 512; q += 16) {
      float v = sA[r * SA_STRIDE + q];
      sum += v; sq += v * v;
    }
    red[r * 16 + s] = sum;
    red[256 + r * 16 + s] = sq;
  }
  __syncthreads();
  if (tid < 16) {
    float sum = 0.f, sq = 0.f;
#pragma unroll
    for (int s = 0; s < 16; ++s) { sum += red[tid * 16 + s]; sq += red[256 + tid * 16 + s]; }
    float mu = sum * (1.f / 512.f);
    float var = sq * (1.f / 512.f) - mu * mu;
    smu[tid] = mu;
    srstd[tid] = rsqrtf(var + LN_EPS);
  }
  __syncthreads();

  // normalize + store out[b][f][t0+m] (16-float contiguous runs per f)
  long long ob = (long long)b * F_ * T_;
  for (int idx = tid; idx < 16 * 512; idx += 256) {
    int f = idx >> 4, m = idx & 15;
    float v = (sA[m * SA_STRIDE + f] - smu[m]) * srstd[m] * lnw[f] + lnb[f];
    out[ob + (long long)f * T_ + t0 + m] = v;
  }
}

// ---------------------------------------------------------------------------
extern "C" void kernel_launch(void* const* d_in, const int* in_sizes, int n_in,
                              void* d_out, int out_size, void* d_ws, size_t ws_size,
                              hipStream_t stream)
{
  const float* bbox      = (const float*)d_in[0];
  const int*   cls       = (const int*)d_in[1];
  const float* edge      = (const float*)d_in[2];
  const float* W_lin     = (const float*)d_in[3];
  const float* emb_table = (const float*)d_in[4];
  const float* W1        = (const float*)d_in[5];
  const float* W2        = (const float*)d_in[6];
  const float* Wm        = (const float*)d_in[7];
  const float* lnw       = (const float*)d_in[8];
  const float* lnb       = (const float*)d_in[9];
  float* out = (float*)d_out;

  // workspace carve-up (total ~143.8 MB)
  float* emb1 = (float*)d_ws;
  float* wbox = emb1 + EMB1_N;
  float* w2t  = wbox + WBOX_N;
  __hip_bfloat16* wm3 = (__hip_bfloat16*)(w2t + W2T_N);
  __hip_bfloat16* h2  = wm3 + WM3_N;

  precompute_small<<<(EMB1_N + WBOX_N + W2T_N) / 256, 256, 0, stream>>>(
      emb_table, W1, W_lin, W2, emb1, wbox, w2t);
  precompute_wm3<<<WM3_N / 256, 256, 0, stream>>>(Wm, wm3);
  k12<<<B_ * T_, 256, 0, stream>>>(bbox, cls, edge, emb1, wbox, w2t, h2);
  k3<<<B_ * T_ / 16, 256, 0, stream>>>(h2, wm3, lnw, lnb, out);
}

// Round 2
// 1528.979 us; speedup vs baseline: 3.2232x; 3.2232x over previous
//
#include <hip/hip_runtime.h>
#include <hip/hip_bf16.h>

// Problem constants
#define B_  4
#define N_  16
#define T_  2048
#define F_  512
#define NC_ 43
constexpr float LN_EPS = 1e-5f;

constexpr int EMB1_N = NC_ * F_;            // 22016
constexpr int WBOX_N = F_ * 4;              // 2048
constexpr int W2T_N  = F_ * F_;             // 262144
constexpr int WMT_N  = F_ * N_ * F_;        // 4194304, wmT[f][k], k=n*F+c
constexpr int K_TOT  = N_ * F_;             // 8192

typedef __bf16 bf16x8_t __attribute__((ext_vector_type(8)));
typedef float  f32x4_t  __attribute__((ext_vector_type(4)));

__device__ __forceinline__ void gload16(const void* g, void* l) {
  __builtin_amdgcn_global_load_lds(
      (const __attribute__((address_space(1))) unsigned int*)g,
      (__attribute__((address_space(3))) unsigned int*)l, 16, 0, 0);
}

// ---------------------------------------------------------------------------
// K0a: emb1[k][f] = sum_c emb_table[k][c] * W1[f][c]
//      wbox[f][q] = sum_c W1[f][F+c] * W_lin[c][q]
//      w2t[c][f]  = W2[f][c]
// ---------------------------------------------------------------------------
__global__ __launch_bounds__(256) void precompute_small(
    const float* __restrict__ emb_table, const float* __restrict__ W1,
    const float* __restrict__ W_lin, const float* __restrict__ W2,
    float* __restrict__ emb1, float* __restrict__ wbox, float* __restrict__ w2t)
{
  int idx = blockIdx.x * 256 + threadIdx.x;
  if (idx < EMB1_N) {
    int k = idx >> 9, f = idx & 511;
    float s = 0.f;
    for (int c = 0; c < F_; ++c) s = fmaf(emb_table[k * F_ + c], W1[f * (2 * F_) + c], s);
    emb1[idx] = s;
  } else if (idx < EMB1_N + WBOX_N) {
    int t2 = idx - EMB1_N;
    int f = t2 >> 2, q = t2 & 3;
    float s = 0.f;
    for (int c = 0; c < F_; ++c) s = fmaf(W1[f * (2 * F_) + F_ + c], W_lin[c * 4 + q], s);
    wbox[t2] = s;
  } else if (idx < EMB1_N + WBOX_N + W2T_N) {
    int t3 = idx - (EMB1_N + WBOX_N);
    int c = t3 >> 9, f = t3 & 511;
    w2t[t3] = W2[f * F_ + c];  // w2t[c][f]
  }
}

// ---------------------------------------------------------------------------
// K0b: wmT[f][k] (bf16), k = n*F + c  <-  Wm[f][c][n]   (B^T layout for MFMA)
// ---------------------------------------------------------------------------
__global__ __launch_bounds__(256) void precompute_wmT(
    const float* __restrict__ Wm, __hip_bfloat16* __restrict__ wmT)
{
  int idx = blockIdx.x * 256 + threadIdx.x;  // idx = f*8192 + n*512 + c
  if (idx < WMT_N) {
    int f = idx >> 13;
    int rem = idx & 8191;
    int n = rem >> 9, c = rem & 511;
    wmT[idx] = __float2bfloat16(Wm[(f * F_ + c) * N_ + n]);
  }
}

// ---------------------------------------------------------------------------
// K12: per pixel p=(b,t): node1 -> h1=relu(em@node1) -> node2=h1@W2^T
//      -> h2=relu(em@node2) -> global bf16, layout h2[p][n*F+c]
// ---------------------------------------------------------------------------
__global__ __launch_bounds__(256) void k12(
    const float* __restrict__ bbox, const int* __restrict__ cls,
    const float* __restrict__ edge, const float* __restrict__ emb1,
    const float* __restrict__ wbox, const float* __restrict__ w2t,
    __hip_bfloat16* __restrict__ h2)
{
  __shared__ __align__(16) float em_s[256];
  __shared__ __align__(16) float bufA[N_ * F_];
  __shared__ __align__(16) float bufB[N_ * F_];
  __shared__ int   cls_s[N_];
  __shared__ float bb_s[N_ * 4];

  const int p = blockIdx.x;
  const int b = p >> 11;
  const int t = p & 2047;
  const int tid = threadIdx.x;

  {
    int i = tid >> 4, j = tid & 15;
    em_s[tid] = edge[(((b * N_ + i) * N_ + j) * T_) + t];
  }
  if (tid < N_) cls_s[tid] = cls[(b * N_ + tid) * T_ + t];
  if (tid < N_ * 4) {
    int j = tid >> 2, q = tid & 3;
    bb_s[tid] = bbox[(((b * N_ + j) * 4 + q) * T_) + t];
  }
  __syncthreads();

  const float4* wb4 = (const float4*)wbox;
  for (int idx = tid; idx < N_ * F_; idx += 256) {
    int j = idx >> 9, f = idx & 511;
    float4 wb = wb4[f];
    float v = emb1[cls_s[j] * F_ + f];
    v = fmaf(bb_s[j * 4 + 0], wb.x, v);
    v = fmaf(bb_s[j * 4 + 1], wb.y, v);
    v = fmaf(bb_s[j * 4 + 2], wb.z, v);
    v = fmaf(bb_s[j * 4 + 3], wb.w, v);
    bufA[idx] = v;
  }
  __syncthreads();

  for (int idx = tid; idx < N_ * F_; idx += 256) {
    int i = idx >> 9, f = idx & 511;
    float s = 0.f;
#pragma unroll
    for (int j = 0; j < N_; ++j) s = fmaf(em_s[i * 16 + j], bufA[j * F_ + f], s);
    bufB[idx] = fmaxf(s, 0.f);
  }
  __syncthreads();

  {
    const int f0 = tid, f1 = tid + 256;
    float acc0[N_], acc1[N_];
#pragma unroll
    for (int j = 0; j < N_; ++j) { acc0[j] = 0.f; acc1[j] = 0.f; }
    for (int c = 0; c < F_; c += 2) {
      float w00 = w2t[c * F_ + f0], w01 = w2t[c * F_ + f1];
      float w10 = w2t[(c + 1) * F_ + f0], w11 = w2t[(c + 1) * F_ + f1];
#pragma unroll
      for (int j = 0; j < N_; ++j) {
        float2 a = *(const float2*)&bufB[j * F_ + c];
        acc0[j] = fmaf(a.x, w00, acc0[j]);
        acc0[j] = fmaf(a.y, w10, acc0[j]);
        acc1[j] = fmaf(a.x, w01, acc1[j]);
        acc1[j] = fmaf(a.y, w11, acc1[j]);
      }
    }
#pragma unroll
    for (int j = 0; j < N_; ++j) {
      bufA[j * F_ + f0] = acc0[j];
      bufA[j * F_ + f1] = acc1[j];
    }
  }
  __syncthreads();

  long long base = (long long)p * (N_ * F_);
  for (int idx = tid; idx < N_ * F_; idx += 256) {
    int i = idx >> 9, f = idx & 511;
    float s = 0.f;
#pragma unroll
    for (int j = 0; j < N_; ++j) s = fmaf(em_s[i * 16 + j], bufA[j * F_ + f], s);
    h2[base + idx] = __float2bfloat16(fmaxf(s, 0.f));
  }
}

// ---------------------------------------------------------------------------
// GEMM (MFMA): feat = h2[8192 x 8192] * wmT^T -> unnormalized out[b][f][t]
// BM=128, BN=64, BK=32; 4 waves, each 64x32 (4x2 tiles of 16x16x32)
// ---------------------------------------------------------------------------
__global__ __launch_bounds__(256) void gemm_feat(
    const __hip_bfloat16* __restrict__ h2g, const __hip_bfloat16* __restrict__ wmTg,
    float* __restrict__ out)
{
  __shared__ __align__(16) char smem[128 * 65 * 4];  // 33280 B (As+Bs carve 12 KB)
  short* As = (short*)smem;                 // [128][32] bf16
  short* Bs = (short*)(smem + 8192);        // [64][32] bf16
  float* sT = (float*)smem;                 // epilogue [128][65]

  const short* h2s  = (const short*)h2g;
  const short* wmTs = (const short*)wmTg;

  const int tid  = threadIdx.x;
  const int bx   = blockIdx.x;
  const int mt   = bx >> 3, nt = bx & 7;
  const long long m0 = (long long)mt * 128;
  const int n0 = nt * 64;

  const int wave = tid >> 6;
  const int lane = tid & 63;
  const int wr = wave >> 1, wc = wave & 1;   // subtile (wr*64, wc*32)

  const int rowS = tid >> 2;                 // staging row 0..63
  const int koff = (tid & 3) * 8;            // staging k-offset (elements)

  const short* aBase = h2s + m0 * K_TOT;
  const short* bBase = wmTs + (long long)n0 * K_TOT;

  f32x4_t acc[4][2];
#pragma unroll
  for (int i = 0; i < 4; ++i)
#pragma unroll
    for (int j = 0; j < 2; ++j)
      acc[i][j] = (f32x4_t){0.f, 0.f, 0.f, 0.f};

  const int mrow = (wr << 6) + (lane & 15);
  const int kq = (lane >> 4) * 8;

  for (int kc = 0; kc < K_TOT; kc += 32) {
    gload16(aBase + (long long)rowS * K_TOT + kc + koff,        As + rowS * 32 + koff);
    gload16(aBase + (long long)(rowS + 64) * K_TOT + kc + koff, As + (rowS + 64) * 32 + koff);
    gload16(bBase + (long long)rowS * K_TOT + kc + koff,        Bs + rowS * 32 + koff);
    __syncthreads();

    bf16x8_t af[4], bf[2];
#pragma unroll
    for (int i = 0; i < 4; ++i)
      af[i] = *(const bf16x8_t*)&As[(mrow + i * 16) * 32 + kq];
#pragma unroll
    for (int j = 0; j < 2; ++j)
      bf[j] = *(const bf16x8_t*)&Bs[((wc << 5) + j * 16 + (lane & 15)) * 32 + kq];

#pragma unroll
    for (int i = 0; i < 4; ++i)
#pragma unroll
      for (int j = 0; j < 2; ++j)
        acc[i][j] = __builtin_amdgcn_mfma_f32_16x16x32_bf16(af[i], bf[j], acc[i][j], 0, 0, 0);
    __syncthreads();
  }

  // epilogue: transpose via LDS, store unnormalized feat into out[b][f][t]
  const int colBase = (wc << 5) + (lane & 15);
  const int rowBase = (wr << 6) + ((lane >> 4) << 2);
#pragma unroll
  for (int i = 0; i < 4; ++i)
#pragma unroll
    for (int j = 0; j < 2; ++j)
#pragma unroll
      for (int r = 0; r < 4; ++r)
        sT[(rowBase + i * 16 + r) * 65 + colBase + j * 16] = acc[i][j][r];
  __syncthreads();

  const int b = (int)(m0 >> 11);
  const int t0 = (int)(m0 & 2047);
  long long ob = (long long)b * (F_ * T_) + (long long)n0 * T_ + t0;
  for (int idx = tid; idx < 128 * 64; idx += 256) {
    int f = idx >> 7, m = idx & 127;
    out[ob + (long long)f * T_ + m] = sT[m * 65 + f];
  }
}

// ---------------------------------------------------------------------------
// LN in-place on out[b][f][t]: per (b,t) normalize over f
// ---------------------------------------------------------------------------
__global__ __launch_bounds__(256) void ln_inplace(
    float* __restrict__ out, const float* __restrict__ lnw, const float* __restrict__ lnb)
{
  __shared__ float sF[F_ * 17];   // [f][m] stride 17
  __shared__ float red[512];
  __shared__ float smu[16], srstd[16];

  const int tid = threadIdx.x;
  const int p0 = blockIdx.x << 4;
  const int b = p0 >> 11, t0 = p0 & 2047;
  long long ob = (long long)b * (F_ * T_) + t0;

  for (int idx = tid; idx < F_ * 16; idx += 256) {
    int f = idx >> 4, m = idx & 15;
    sF[f * 17 + m] = out[ob + (long long)f * T_ + m];
  }
  __syncthreads();

  {
    int m = tid & 15, s = tid >> 4;
    float sum = 0.f, sq = 0.f;
    for (int f = s; f < F_; f += 16) {
      float v = sF[f * 17 + m];
      sum += v; sq += v * v;
    }
    red[tid] = sum;
    red[256 + tid] = sq;
  }
  __syncthreads();
  if (tid < 16) {
    float sum = 0.f, sq = 0.f;
#pragma unroll
    for (int s = 0; s < 16; ++s) { sum += red[s * 16 + tid]; sq += red[256 + s * 16 + tid]; }
    float mu = sum * (1.f / F_);
    float var = sq * (1.f / F_) - mu * mu;
    smu[tid] = mu;
    srstd[tid] = rsqrtf(var + LN_EPS);
  }
  __syncthreads();

  for (int idx = tid; idx < F_ * 16; idx += 256) {
    int f = idx >> 4, m = idx & 15;
    float v = (sF[f * 17 + m] - smu[m]) * srstd[m] * lnw[f] + lnb[f];
    out[ob + (long long)f * T_ + m] = v;
  }
}

// ---------------------------------------------------------------------------
extern "C" void kernel_launch(void* const* d_in, const int* in_sizes, int n_in,
                              void* d_out, int out_size, void* d_ws, size_t ws_size,
                              hipStream_t stream)
{
  const float* bbox      = (const float*)d_in[0];
  const int*   cls       = (const int*)d_in[1];
  const float* edge      = (const float*)d_in[2];
  const float* W_lin     = (const float*)d_in[3];
  const float* emb_table = (const float*)d_in[4];
  const float* W1        = (const float*)d_in[5];
  const float* W2        = (const float*)d_in[6];
  const float* Wm        = (const float*)d_in[7];
  const float* lnw       = (const float*)d_in[8];
  const float* lnb       = (const float*)d_in[9];
  float* out = (float*)d_out;

  // workspace carve-up (~143.8 MB, same as round 1)
  float* emb1 = (float*)d_ws;
  float* wbox = emb1 + EMB1_N;
  float* w2t  = wbox + WBOX_N;
  __hip_bfloat16* wmT = (__hip_bfloat16*)(w2t + W2T_N);
  __hip_bfloat16* h2  = wmT + WMT_N;

  precompute_small<<<(EMB1_N + WBOX_N + W2T_N) / 256, 256, 0, stream>>>(
      emb_table, W1, W_lin, W2, emb1, wbox, w2t);
  precompute_wmT<<<WMT_N / 256, 256, 0, stream>>>(Wm, wmT);
  k12<<<B_ * T_, 256, 0, stream>>>(bbox, cls, edge, emb1, wbox, w2t, h2);
  gemm_feat<<<512, 256, 0, stream>>>(h2, wmT, out);
  ln_inplace<<<B_ * T_ / 16, 256, 0, stream>>>(out, lnw, lnb);
}

// Round 3
// 612.603 us; speedup vs baseline: 8.0447x; 2.4959x over previous
//
#include <hip/hip_runtime.h>
#include <hip/hip_bf16.h>

// Problem constants
#define B_  4
#define N_  16
#define T_  2048
#define F_  512
#define NC_ 43
constexpr float LN_EPS = 1e-5f;

constexpr int EMB1_N = NC_ * F_;            // 22016 (fp32)
constexpr int WBOX_N = F_ * 4;              // 2048  (fp32)
constexpr int W2BF_N = F_ * F_;             // 262144 (bf16) native [f][c]
constexpr int WMT_N  = F_ * N_ * F_;        // 4194304 (bf16), wmT[f][k], k=n*F+c
constexpr int K_TOT  = N_ * F_;             // 8192

typedef __bf16 bf16x8_t __attribute__((ext_vector_type(8)));
typedef float  f32x4_t  __attribute__((ext_vector_type(4)));

__device__ __forceinline__ void gload16(const void* g, void* l) {
  __builtin_amdgcn_global_load_lds(
      (const __attribute__((address_space(1))) unsigned int*)g,
      (__attribute__((address_space(3))) unsigned int*)l, 16, 0, 0);
}

// ---------------------------------------------------------------------------
// K0a: emb1[k][f] = sum_c emb_table[k][c] * W1[f][c]
//      wbox[f][q] = sum_c W1[f][F+c] * W_lin[c][q]
//      w2bf[f][c] = bf16(W2[f][c])   (B^T layout for MFMA = native W2)
// ---------------------------------------------------------------------------
__global__ __launch_bounds__(256) void precompute_small(
    const float* __restrict__ emb_table, const float* __restrict__ W1,
    const float* __restrict__ W_lin, const float* __restrict__ W2,
    float* __restrict__ emb1, float* __restrict__ wbox,
    __hip_bfloat16* __restrict__ w2bf)
{
  int idx = blockIdx.x * 256 + threadIdx.x;
  if (idx < EMB1_N) {
    int k = idx >> 9, f = idx & 511;
    float s = 0.f;
    for (int c = 0; c < F_; ++c) s = fmaf(emb_table[k * F_ + c], W1[f * (2 * F_) + c], s);
    emb1[idx] = s;
  } else if (idx < EMB1_N + WBOX_N) {
    int t2 = idx - EMB1_N;
    int f = t2 >> 2, q = t2 & 3;
    float s = 0.f;
    for (int c = 0; c < F_; ++c) s = fmaf(W1[f * (2 * F_) + F_ + c], W_lin[c * 4 + q], s);
    wbox[t2] = s;
  } else if (idx < EMB1_N + WBOX_N + W2BF_N) {
    int t3 = idx - (EMB1_N + WBOX_N);
    w2bf[t3] = __float2bfloat16(W2[t3]);
  }
}

// ---------------------------------------------------------------------------
// K0b: wmT[f][k] (bf16), k = n*F + c  <-  Wm[f][c][n]
// ---------------------------------------------------------------------------
__global__ __launch_bounds__(256) void precompute_wmT(
    const float* __restrict__ Wm, __hip_bfloat16* __restrict__ wmT)
{
  int idx = blockIdx.x * 256 + threadIdx.x;  // idx = f*8192 + n*512 + c
  if (idx < WMT_N) {
    int f = idx >> 13;
    int rem = idx & 8191;
    int n = rem >> 9, c = rem & 511;
    wmT[idx] = __float2bfloat16(Wm[(f * F_ + c) * N_ + n]);
  }
}

// ---------------------------------------------------------------------------
// k_h1g: per pixel p=(b,t):
//   node1[j][f] = emb1[cls[j]][f] + bbox.wbox       (fp32, LDS)
//   h1 = relu(em @ node1)                           (fp32, LDS)
//   g  = em @ h1                                    -> global bf16 [p*16+i][c]
// (second em-mix hoisted here by associativity: relu(em@(h1@W2^T)) == relu((em@h1)@W2^T))
// ---------------------------------------------------------------------------
__global__ __launch_bounds__(256) void k_h1g(
    const float* __restrict__ bbox, const int* __restrict__ cls,
    const float* __restrict__ edge, const float* __restrict__ emb1,
    const float* __restrict__ wbox, __hip_bfloat16* __restrict__ g)
{
  __shared__ float em_s[256];
  __shared__ __align__(16) float bufA[N_ * F_];
  __shared__ __align__(16) float bufB[N_ * F_];
  __shared__ int   cls_s[N_];
  __shared__ float bb_s[N_ * 4];

  const int p = blockIdx.x;
  const int b = p >> 11;
  const int t = p & 2047;
  const int tid = threadIdx.x;

  {
    int i = tid >> 4, j = tid & 15;
    em_s[tid] = edge[(((b * N_ + i) * N_ + j) * T_) + t];
  }
  if (tid < N_) cls_s[tid] = cls[(b * N_ + tid) * T_ + t];
  if (tid < N_ * 4) {
    int j = tid >> 2, q = tid & 3;
    bb_s[tid] = bbox[(((b * N_ + j) * 4 + q) * T_) + t];
  }
  __syncthreads();

  // S1: node1 -> bufA
  const float4* wb4 = (const float4*)wbox;
  for (int idx = tid; idx < N_ * F_; idx += 256) {
    int j = idx >> 9, f = idx & 511;
    float4 wb = wb4[f];
    float v = emb1[cls_s[j] * F_ + f];
    v = fmaf(bb_s[j * 4 + 0], wb.x, v);
    v = fmaf(bb_s[j * 4 + 1], wb.y, v);
    v = fmaf(bb_s[j * 4 + 2], wb.z, v);
    v = fmaf(bb_s[j * 4 + 3], wb.w, v);
    bufA[idx] = v;
  }
  __syncthreads();

  // cache this wave's 4 em rows in registers
  const int w = tid >> 6, lane = tid & 63;
  float emr[4][16];
#pragma unroll
  for (int r = 0; r < 4; ++r)
#pragma unroll
    for (int j = 0; j < 16; ++j) emr[r][j] = em_s[(w * 4 + r) * 16 + j];

  // S2: h1 = relu(em @ node1) -> bufB  (wave w owns rows 4w..4w+3)
#pragma unroll
  for (int chunk = 0; chunk < 2; ++chunk) {
    const int c0 = chunk * 256 + lane * 4;
    float4 a0 = {0, 0, 0, 0}, a1 = {0, 0, 0, 0}, a2 = {0, 0, 0, 0}, a3 = {0, 0, 0, 0};
#pragma unroll
    for (int j = 0; j < 16; ++j) {
      float4 v = *(const float4*)&bufA[j * F_ + c0];
      a0.x = fmaf(emr[0][j], v.x, a0.x); a0.y = fmaf(emr[0][j], v.y, a0.y);
      a0.z = fmaf(emr[0][j], v.z, a0.z); a0.w = fmaf(emr[0][j], v.w, a0.w);
      a1.x = fmaf(emr[1][j], v.x, a1.x); a1.y = fmaf(emr[1][j], v.y, a1.y);
      a1.z = fmaf(emr[1][j], v.z, a1.z); a1.w = fmaf(emr[1][j], v.w, a1.w);
      a2.x = fmaf(emr[2][j], v.x, a2.x); a2.y = fmaf(emr[2][j], v.y, a2.y);
      a2.z = fmaf(emr[2][j], v.z, a2.z); a2.w = fmaf(emr[2][j], v.w, a2.w);
      a3.x = fmaf(emr[3][j], v.x, a3.x); a3.y = fmaf(emr[3][j], v.y, a3.y);
      a3.z = fmaf(emr[3][j], v.z, a3.z); a3.w = fmaf(emr[3][j], v.w, a3.w);
    }
    a0.x = fmaxf(a0.x, 0.f); a0.y = fmaxf(a0.y, 0.f); a0.z = fmaxf(a0.z, 0.f); a0.w = fmaxf(a0.w, 0.f);
    a1.x = fmaxf(a1.x, 0.f); a1.y = fmaxf(a1.y, 0.f); a1.z = fmaxf(a1.z, 0.f); a1.w = fmaxf(a1.w, 0.f);
    a2.x = fmaxf(a2.x, 0.f); a2.y = fmaxf(a2.y, 0.f); a2.z = fmaxf(a2.z, 0.f); a2.w = fmaxf(a2.w, 0.f);
    a3.x = fmaxf(a3.x, 0.f); a3.y = fmaxf(a3.y, 0.f); a3.z = fmaxf(a3.z, 0.f); a3.w = fmaxf(a3.w, 0.f);
    *(float4*)&bufB[(w * 4 + 0) * F_ + c0] = a0;
    *(float4*)&bufB[(w * 4 + 1) * F_ + c0] = a1;
    *(float4*)&bufB[(w * 4 + 2) * F_ + c0] = a2;
    *(float4*)&bufB[(w * 4 + 3) * F_ + c0] = a3;
  }
  __syncthreads();

  // S3: g = em @ h1 -> global bf16 (no relu)
  long long base = (long long)p * (N_ * F_);
  short* gs = (short*)g;
#pragma unroll
  for (int chunk = 0; chunk < 2; ++chunk) {
    const int c0 = chunk * 256 + lane * 4;
    float4 a0 = {0, 0, 0, 0}, a1 = {0, 0, 0, 0}, a2 = {0, 0, 0, 0}, a3 = {0, 0, 0, 0};
#pragma unroll
    for (int j = 0; j < 16; ++j) {
      float4 v = *(const float4*)&bufB[j * F_ + c0];
      a0.x = fmaf(emr[0][j], v.x, a0.x); a0.y = fmaf(emr[0][j], v.y, a0.y);
      a0.z = fmaf(emr[0][j], v.z, a0.z); a0.w = fmaf(emr[0][j], v.w, a0.w);
      a1.x = fmaf(emr[1][j], v.x, a1.x); a1.y = fmaf(emr[1][j], v.y, a1.y);
      a1.z = fmaf(emr[1][j], v.z, a1.z); a1.w = fmaf(emr[1][j], v.w, a1.w);
      a2.x = fmaf(emr[2][j], v.x, a2.x); a2.y = fmaf(emr[2][j], v.y, a2.y);
      a2.z = fmaf(emr[2][j], v.z, a2.z); a2.w = fmaf(emr[2][j], v.w, a2.w);
      a3.x = fmaf(emr[3][j], v.x, a3.x); a3.y = fmaf(emr[3][j], v.y, a3.y);
      a3.z = fmaf(emr[3][j], v.z, a3.z); a3.w = fmaf(emr[3][j], v.w, a3.w);
    }
#pragma unroll
    for (int r = 0; r < 4; ++r) {
      float4 ar = (r == 0) ? a0 : (r == 1) ? a1 : (r == 2) ? a2 : a3;
      short4 sv;
      sv.x = (short)__bfloat16_as_ushort(__float2bfloat16(ar.x));
      sv.y = (short)__bfloat16_as_ushort(__float2bfloat16(ar.y));
      sv.z = (short)__bfloat16_as_ushort(__float2bfloat16(ar.z));
      sv.w = (short)__bfloat16_as_ushort(__float2bfloat16(ar.w));
      *(short4*)&gs[base + (w * 4 + r) * F_ + c0] = sv;
    }
  }
}

// ---------------------------------------------------------------------------
// gemm_h2 (MFMA): h2 = relu(g @ w2bf^T), IN-PLACE on gbuf.
// BM=64, BN=512 (full), BK=32; grid 2048; 4 waves, wave owns 128 output cols.
// BN=512 => each block exclusively owns its 64 rows -> in-place is race-free.
// ---------------------------------------------------------------------------
__global__ __launch_bounds__(256, 2) void gemm_h2(
    __hip_bfloat16* __restrict__ gbuf, const __hip_bfloat16* __restrict__ w2bf)
{
  __shared__ __align__(16) short As[64 * 32];   // 4 KB
  __shared__ __align__(16) short Bs[512 * 32];  // 32 KB

  short* gs = (short*)gbuf;
  const short* ws = (const short*)w2bf;

  const int tid = threadIdx.x;
  const long long m0 = (long long)blockIdx.x * 64;
  const int wave = tid >> 6, lane = tid & 63;
  const int rowA = tid >> 2, koff = (tid & 3) * 8;
  const int mrow = lane & 15, kq = (lane >> 4) * 8;

  f32x4_t acc[4][8];
#pragma unroll
  for (int i = 0; i < 4; ++i)
#pragma unroll
    for (int j = 0; j < 8; ++j) acc[i][j] = (f32x4_t){0.f, 0.f, 0.f, 0.f};

  for (int kc = 0; kc < F_; kc += 32) {
    gload16(gs + (m0 + rowA) * F_ + kc + koff, As + rowA * 32 + koff);
#pragma unroll
    for (int it = 0; it < 8; ++it)
      gload16(ws + (it * 64 + rowA) * F_ + kc + koff, Bs + (it * 64 + rowA) * 32 + koff);
    __syncthreads();

    bf16x8_t af[4], bfr[8];
#pragma unroll
    for (int i = 0; i < 4; ++i)
      af[i] = *(const bf16x8_t*)&As[(i * 16 + mrow) * 32 + kq];
#pragma unroll
    for (int j = 0; j < 8; ++j)
      bfr[j] = *(const bf16x8_t*)&Bs[((wave << 7) + j * 16 + mrow) * 32 + kq];

#pragma unroll
    for (int i = 0; i < 4; ++i)
#pragma unroll
      for (int j = 0; j < 8; ++j)
        acc[i][j] = __builtin_amdgcn_mfma_f32_16x16x32_bf16(af[i], bfr[j], acc[i][j], 0, 0, 0);
    __syncthreads();
  }

  // epilogue: relu -> bf16, in-place store (rows owned exclusively by this block)
  const int rbase = (lane >> 4) * 2 * 2;  // (lane>>4)*4
#pragma unroll
  for (int i = 0; i < 4; ++i)
#pragma unroll
    for (int j = 0; j < 8; ++j)
#pragma unroll
      for (int r = 0; r < 4; ++r) {
        int row = i * 16 + rbase + r;
        int col = (wave << 7) + j * 16 + mrow;
        float v = fmaxf(acc[i][j][r], 0.f);
        gs[(m0 + row) * F_ + col] = (short)__bfloat16_as_ushort(__float2bfloat16(v));
      }
}

// ---------------------------------------------------------------------------
// GEMM (MFMA): feat = h2[8192 x 8192] * wmT^T -> unnormalized out[b][f][t]
// BM=128, BN=64, BK=32; 4 waves, each 64x32 (4x2 tiles of 16x16x32)
// ---------------------------------------------------------------------------
__global__ __launch_bounds__(256) void gemm_feat(
    const __hip_bfloat16* __restrict__ h2g, const __hip_bfloat16* __restrict__ wmTg,
    float* __restrict__ out)
{
  __shared__ __align__(16) char smem[128 * 65 * 4];  // 33280 B (As+Bs carve 12 KB)
  short* As = (short*)smem;                 // [128][32] bf16
  short* Bs = (short*)(smem + 8192);        // [64][32] bf16
  float* sT = (float*)smem;                 // epilogue [128][65]

  const short* h2s  = (const short*)h2g;
  const short* wmTs = (const short*)wmTg;

  const int tid  = threadIdx.x;
  const int bx   = blockIdx.x;
  const int mt   = bx >> 3, nt = bx & 7;
  const long long m0 = (long long)mt * 128;
  const int n0 = nt * 64;

  const int wave = tid >> 6;
  const int lane = tid & 63;
  const int wr = wave >> 1, wc = wave & 1;   // subtile (wr*64, wc*32)

  const int rowS = tid >> 2;                 // staging row 0..63
  const int koff = (tid & 3) * 8;            // staging k-offset (elements)

  const short* aBase = h2s + m0 * K_TOT;
  const short* bBase = wmTs + (long long)n0 * K_TOT;

  f32x4_t acc[4][2];
#pragma unroll
  for (int i = 0; i < 4; ++i)
#pragma unroll
    for (int j = 0; j < 2; ++j)
      acc[i][j] = (f32x4_t){0.f, 0.f, 0.f, 0.f};

  const int mrow = (wr << 6) + (lane & 15);
  const int kq = (lane >> 4) * 8;

  for (int kc = 0; kc < K_TOT; kc += 32) {
    gload16(aBase + (long long)rowS * K_TOT + kc + koff,        As + rowS * 32 + koff);
    gload16(aBase + (long long)(rowS + 64) * K_TOT + kc + koff, As + (rowS + 64) * 32 + koff);
    gload16(bBase + (long long)rowS * K_TOT + kc + koff,        Bs + rowS * 32 + koff);
    __syncthreads();

    bf16x8_t af[4], bfr[2];
#pragma unroll
    for (int i = 0; i < 4; ++i)
      af[i] = *(const bf16x8_t*)&As[(mrow + i * 16) * 32 + kq];
#pragma unroll
    for (int j = 0; j < 2; ++j)
      bfr[j] = *(const bf16x8_t*)&Bs[((wc << 5) + j * 16 + (lane & 15)) * 32 + kq];

#pragma unroll
    for (int i = 0; i < 4; ++i)
#pragma unroll
      for (int j = 0; j < 2; ++j)
        acc[i][j] = __builtin_amdgcn_mfma_f32_16x16x32_bf16(af[i], bfr[j], acc[i][j], 0, 0, 0);
    __syncthreads();
  }

  // epilogue: transpose via LDS, store unnormalized feat into out[b][f][t]
  const int colBase = (wc << 5) + (lane & 15);
  const int rowBase = (wr << 6) + ((lane >> 4) << 2);
#pragma unroll
  for (int i = 0; i < 4; ++i)
#pragma unroll
    for (int j = 0; j < 2; ++j)
#pragma unroll
      for (int r = 0; r < 4; ++r)
        sT[(rowBase + i * 16 + r) * 65 + colBase + j * 16] = acc[i][j][r];
  __syncthreads();

  const int b = (int)(m0 >> 11);
  const int t0 = (int)(m0 & 2047);
  long long ob = (long long)b * (F_ * T_) + (long long)n0 * T_ + t0;
  for (int idx = tid; idx < 128 * 64; idx += 256) {
    int f = idx >> 7, m = idx & 127;
    out[ob + (long long)f * T_ + m] = sT[m * 65 + f];
  }
}

// ---------------------------------------------------------------------------
// LN in-place on out[b][f][t]: per (b,t) normalize over f
// ---------------------------------------------------------------------------
__global__ __launch_bounds__(256) void ln_inplace(
    float* __restrict__ out, const float* __restrict__ lnw, const float* __restrict__ lnb)
{
  __shared__ float sF[F_ * 17];   // [f][m] stride 17
  __shared__ float red[512];
  __shared__ float smu[16], srstd[16];

  const int tid = threadIdx.x;
  const int p0 = blockIdx.x << 4;
  const int b = p0 >> 11, t0 = p0 & 2047;
  long long ob = (long long)b * (F_ * T_) + t0;

  for (int idx = tid; idx < F_ * 16; idx += 256) {
    int f = idx >> 4, m = idx & 15;
    sF[f * 17 + m] = out[ob + (long long)f * T_ + m];
  }
  __syncthreads();

  {
    int m = tid & 15, s = tid >> 4;
    float sum = 0.f, sq = 0.f;
    for (int f = s; f < F_; f += 16) {
      float v = sF[f * 17 + m];
      sum += v; sq += v * v;
    }
    red[tid] = sum;
    red[256 + tid] = sq;
  }
  __syncthreads();
  if (tid < 16) {
    float sum = 0.f, sq = 0.f;
#pragma unroll
    for (int s = 0; s < 16; ++s) { sum += red[s * 16 + tid]; sq += red[256 + s * 16 + tid]; }
    float mu = sum * (1.f / F_);
    float var = sq * (1.f / F_) - mu * mu;
    smu[tid] = mu;
    srstd[tid] = rsqrtf(var + LN_EPS);
  }
  __syncthreads();

  for (int idx = tid; idx < F_ * 16; idx += 256) {
    int f = idx >> 4, m = idx & 15;
    float v = (sF[f * 17 + m] - smu[m]) * srstd[m] * lnw[f] + lnb[f];
    out[ob + (long long)f * T_ + m] = v;
  }
}

// ---------------------------------------------------------------------------
extern "C" void kernel_launch(void* const* d_in, const int* in_sizes, int n_in,
                              void* d_out, int out_size, void* d_ws, size_t ws_size,
                              hipStream_t stream)
{
  const float* bbox      = (const float*)d_in[0];
  const int*   cls       = (const int*)d_in[1];
  const float* edge      = (const float*)d_in[2];
  const float* W_lin     = (const float*)d_in[3];
  const float* emb_table = (const float*)d_in[4];
  const float* W1        = (const float*)d_in[5];
  const float* W2        = (const float*)d_in[6];
  const float* Wm        = (const float*)d_in[7];
  const float* lnw       = (const float*)d_in[8];
  const float* lnb       = (const float*)d_in[9];
  float* out = (float*)d_out;

  // workspace carve-up (~143.2 MB, <= proven r1 footprint)
  float* emb1 = (float*)d_ws;
  float* wbox = emb1 + EMB1_N;
  __hip_bfloat16* w2bf = (__hip_bfloat16*)(wbox + WBOX_N);
  __hip_bfloat16* wmT  = w2bf + W2BF_N;
  __hip_bfloat16* gbuf = wmT + WMT_N;   // g, then h2 in-place

  precompute_small<<<(EMB1_N + WBOX_N + W2BF_N) / 256, 256, 0, stream>>>(
      emb_table, W1, W_lin, W2, emb1, wbox, w2bf);
  precompute_wmT<<<WMT_N / 256, 256, 0, stream>>>(Wm, wmT);
  k_h1g<<<B_ * T_, 256, 0, stream>>>(bbox, cls, edge, emb1, wbox, gbuf);
  gemm_h2<<<B_ * T_ * N_ / 64, 256, 0, stream>>>(gbuf, w2bf);
  gemm_feat<<<512, 256, 0, stream>>>(gbuf, wmT, out);
  ln_inplace<<<B_ * T_ / 16, 256, 0, stream>>>(out, lnw, lnb);
}

// Round 4
// 575.893 us; speedup vs baseline: 8.5576x; 1.0637x over previous
//
#include <hip/hip_runtime.h>
#include <hip/hip_bf16.h>

// Problem constants
#define B_  4
#define N_  16
#define T_  2048
#define F_  512
#define NC_ 43
constexpr float LN_EPS = 1e-5f;

constexpr int EMB1_N = NC_ * F_;            // 22016 (fp32)
constexpr int WBOX_N = F_ * 4;              // 2048  (fp32)
constexpr int W2BF_N = F_ * F_;             // 262144 (bf16) native [f][c]
constexpr int WMT_N  = F_ * N_ * F_;        // 4194304 (bf16), wmT[f][k], k=n*F+c
constexpr int K_TOT  = N_ * F_;             // 8192

typedef __bf16 bf16x8_t __attribute__((ext_vector_type(8)));
typedef float  f32x4_t  __attribute__((ext_vector_type(4)));

__device__ __forceinline__ void gload16(const void* g, void* l) {
  __builtin_amdgcn_global_load_lds(
      (const __attribute__((address_space(1))) unsigned int*)g,
      (__attribute__((address_space(3))) unsigned int*)l, 16, 0, 0);
}

// ---------------------------------------------------------------------------
// K0a: emb1[k][f] = sum_c emb_table[k][c] * W1[f][c]
//      wbox[f][q] = sum_c W1[f][F+c] * W_lin[c][q]
//      w2bf[f][c] = bf16(W2[f][c])
// ---------------------------------------------------------------------------
__global__ __launch_bounds__(256) void precompute_small(
    const float* __restrict__ emb_table, const float* __restrict__ W1,
    const float* __restrict__ W_lin, const float* __restrict__ W2,
    float* __restrict__ emb1, float* __restrict__ wbox,
    __hip_bfloat16* __restrict__ w2bf)
{
  int idx = blockIdx.x * 256 + threadIdx.x;
  if (idx < EMB1_N) {
    int k = idx >> 9, f = idx & 511;
    const float4* et = (const float4*)&emb_table[k * F_];
    const float4* w1 = (const float4*)&W1[f * (2 * F_)];
    float s = 0.f;
    for (int c4 = 0; c4 < F_ / 4; ++c4) {
      float4 a = et[c4], b = w1[c4];
      s = fmaf(a.x, b.x, s); s = fmaf(a.y, b.y, s);
      s = fmaf(a.z, b.z, s); s = fmaf(a.w, b.w, s);
    }
    emb1[idx] = s;
  } else if (idx < EMB1_N + WBOX_N) {
    int t2 = idx - EMB1_N;
    int f = t2 >> 2, q = t2 & 3;
    const float4* w1 = (const float4*)&W1[f * (2 * F_) + F_];
    float s = 0.f;
    for (int c4 = 0; c4 < F_ / 4; ++c4) {
      float4 a = w1[c4];
      s = fmaf(a.x, W_lin[(c4 * 4 + 0) * 4 + q], s);
      s = fmaf(a.y, W_lin[(c4 * 4 + 1) * 4 + q], s);
      s = fmaf(a.z, W_lin[(c4 * 4 + 2) * 4 + q], s);
      s = fmaf(a.w, W_lin[(c4 * 4 + 3) * 4 + q], s);
    }
    wbox[t2] = s;
  } else if (idx < EMB1_N + WBOX_N + W2BF_N) {
    int t3 = idx - (EMB1_N + WBOX_N);
    w2bf[t3] = __float2bfloat16(W2[t3]);
  }
}

// ---------------------------------------------------------------------------
// K0b: wmT[f][k] (bf16), k = n*F + c  <-  Wm[f][c][n]
// ---------------------------------------------------------------------------
__global__ __launch_bounds__(256) void precompute_wmT(
    const float* __restrict__ Wm, __hip_bfloat16* __restrict__ wmT)
{
  int idx = blockIdx.x * 256 + threadIdx.x;  // idx = f*8192 + n*512 + c
  if (idx < WMT_N) {
    int f = idx >> 13;
    int rem = idx & 8191;
    int n = rem >> 9, c = rem & 511;
    wmT[idx] = __float2bfloat16(Wm[(f * F_ + c) * N_ + n]);
  }
}

// ---------------------------------------------------------------------------
// k_h1g: per pixel p=(b,t): node1 -> h1=relu(em@node1) -> g=em@h1 -> bf16
// (second em-mix hoisted by associativity: relu(em@(h1@W2^T)) == relu((em@h1)@W2^T))
// ---------------------------------------------------------------------------
__global__ __launch_bounds__(256) void k_h1g(
    const float* __restrict__ bbox, const int* __restrict__ cls,
    const float* __restrict__ edge, const float* __restrict__ emb1,
    const float* __restrict__ wbox, __hip_bfloat16* __restrict__ g)
{
  __shared__ float em_s[256];
  __shared__ __align__(16) float bufA[N_ * F_];
  __shared__ __align__(16) float bufB[N_ * F_];
  __shared__ int   cls_s[N_];
  __shared__ float bb_s[N_ * 4];

  const int p = blockIdx.x;
  const int b = p >> 11;
  const int t = p & 2047;
  const int tid = threadIdx.x;

  {
    int i = tid >> 4, j = tid & 15;
    em_s[tid] = edge[(((b * N_ + i) * N_ + j) * T_) + t];
  }
  if (tid < N_) cls_s[tid] = cls[(b * N_ + tid) * T_ + t];
  if (tid < N_ * 4) {
    int j = tid >> 2, q = tid & 3;
    bb_s[tid] = bbox[(((b * N_ + j) * 4 + q) * T_) + t];
  }
  __syncthreads();

  const float4* wb4 = (const float4*)wbox;
  for (int idx = tid; idx < N_ * F_; idx += 256) {
    int j = idx >> 9, f = idx & 511;
    float4 wb = wb4[f];
    float v = emb1[cls_s[j] * F_ + f];
    v = fmaf(bb_s[j * 4 + 0], wb.x, v);
    v = fmaf(bb_s[j * 4 + 1], wb.y, v);
    v = fmaf(bb_s[j * 4 + 2], wb.z, v);
    v = fmaf(bb_s[j * 4 + 3], wb.w, v);
    bufA[idx] = v;
  }
  __syncthreads();

  const int w = tid >> 6, lane = tid & 63;
  float emr[4][16];
#pragma unroll
  for (int r = 0; r < 4; ++r)
#pragma unroll
    for (int j = 0; j < 16; ++j) emr[r][j] = em_s[(w * 4 + r) * 16 + j];

#pragma unroll
  for (int chunk = 0; chunk < 2; ++chunk) {
    const int c0 = chunk * 256 + lane * 4;
    float4 a0 = {0, 0, 0, 0}, a1 = {0, 0, 0, 0}, a2 = {0, 0, 0, 0}, a3 = {0, 0, 0, 0};
#pragma unroll
    for (int j = 0; j < 16; ++j) {
      float4 v = *(const float4*)&bufA[j * F_ + c0];
      a0.x = fmaf(emr[0][j], v.x, a0.x); a0.y = fmaf(emr[0][j], v.y, a0.y);
      a0.z = fmaf(emr[0][j], v.z, a0.z); a0.w = fmaf(emr[0][j], v.w, a0.w);
      a1.x = fmaf(emr[1][j], v.x, a1.x); a1.y = fmaf(emr[1][j], v.y, a1.y);
      a1.z = fmaf(emr[1][j], v.z, a1.z); a1.w = fmaf(emr[1][j], v.w, a1.w);
      a2.x = fmaf(emr[2][j], v.x, a2.x); a2.y = fmaf(emr[2][j], v.y, a2.y);
      a2.z = fmaf(emr[2][j], v.z, a2.z); a2.w = fmaf(emr[2][j], v.w, a2.w);
      a3.x = fmaf(emr[3][j], v.x, a3.x); a3.y = fmaf(emr[3][j], v.y, a3.y);
      a3.z = fmaf(emr[3][j], v.z, a3.z); a3.w = fmaf(emr[3][j], v.w, a3.w);
    }
    a0.x = fmaxf(a0.x, 0.f); a0.y = fmaxf(a0.y, 0.f); a0.z = fmaxf(a0.z, 0.f); a0.w = fmaxf(a0.w, 0.f);
    a1.x = fmaxf(a1.x, 0.f); a1.y = fmaxf(a1.y, 0.f); a1.z = fmaxf(a1.z, 0.f); a1.w = fmaxf(a1.w, 0.f);
    a2.x = fmaxf(a2.x, 0.f); a2.y = fmaxf(a2.y, 0.f); a2.z = fmaxf(a2.z, 0.f); a2.w = fmaxf(a2.w, 0.f);
    a3.x = fmaxf(a3.x, 0.f); a3.y = fmaxf(a3.y, 0.f); a3.z = fmaxf(a3.z, 0.f); a3.w = fmaxf(a3.w, 0.f);
    *(float4*)&bufB[(w * 4 + 0) * F_ + c0] = a0;
    *(float4*)&bufB[(w * 4 + 1) * F_ + c0] = a1;
    *(float4*)&bufB[(w * 4 + 2) * F_ + c0] = a2;
    *(float4*)&bufB[(w * 4 + 3) * F_ + c0] = a3;
  }
  __syncthreads();

  long long base = (long long)p * (N_ * F_);
  short* gs = (short*)g;
#pragma unroll
  for (int chunk = 0; chunk < 2; ++chunk) {
    const int c0 = chunk * 256 + lane * 4;
    float4 a0 = {0, 0, 0, 0}, a1 = {0, 0, 0, 0}, a2 = {0, 0, 0, 0}, a3 = {0, 0, 0, 0};
#pragma unroll
    for (int j = 0; j < 16; ++j) {
      float4 v = *(const float4*)&bufB[j * F_ + c0];
      a0.x = fmaf(emr[0][j], v.x, a0.x); a0.y = fmaf(emr[0][j], v.y, a0.y);
      a0.z = fmaf(emr[0][j], v.z, a0.z); a0.w = fmaf(emr[0][j], v.w, a0.w);
      a1.x = fmaf(emr[1][j], v.x, a1.x); a1.y = fmaf(emr[1][j], v.y, a1.y);
      a1.z = fmaf(emr[1][j], v.z, a1.z); a1.w = fmaf(emr[1][j], v.w, a1.w);
      a2.x = fmaf(emr[2][j], v.x, a2.x); a2.y = fmaf(emr[2][j], v.y, a2.y);
      a2.z = fmaf(emr[2][j], v.z, a2.z); a2.w = fmaf(emr[2][j], v.w, a2.w);
      a3.x = fmaf(emr[3][j], v.x, a3.x); a3.y = fmaf(emr[3][j], v.y, a3.y);
      a3.z = fmaf(emr[3][j], v.z, a3.z); a3.w = fmaf(emr[3][j], v.w, a3.w);
    }
#pragma unroll
    for (int r = 0; r < 4; ++r) {
      float4 ar = (r == 0) ? a0 : (r == 1) ? a1 : (r == 2) ? a2 : a3;
      short4 sv;
      sv.x = (short)__bfloat16_as_ushort(__float2bfloat16(ar.x));
      sv.y = (short)__bfloat16_as_ushort(__float2bfloat16(ar.y));
      sv.z = (short)__bfloat16_as_ushort(__float2bfloat16(ar.z));
      sv.w = (short)__bfloat16_as_ushort(__float2bfloat16(ar.w));
      *(short4*)&gs[base + (w * 4 + r) * F_ + c0] = sv;
    }
  }
}

// ---------------------------------------------------------------------------
// gemm_h2 (MFMA): h2 = relu(g @ w2bf^T), IN-PLACE on gbuf.
// BM=128, BN=512(full), BK=32; 512 threads (8 waves, 2x4), grid 1024.
// BN=512 => block exclusively owns its rows -> in-place race-free.
// ---------------------------------------------------------------------------
__global__ __launch_bounds__(512, 2) void gemm_h2(
    __hip_bfloat16* __restrict__ gbuf, const __hip_bfloat16* __restrict__ w2bf)
{
  __shared__ __align__(16) short As[128 * 32];  // 8 KB
  __shared__ __align__(16) short Bs[512 * 32];  // 32 KB

  short* gs = (short*)gbuf;
  const short* ws = (const short*)w2bf;

  const int tid = threadIdx.x;
  const long long m0 = (long long)blockIdx.x * 128;
  const int wave8 = tid >> 6, lane = tid & 63;
  const int wr = wave8 >> 2, wcol = wave8 & 3;   // wave tile: rows wr*64, cols wcol*128
  const int rowU = tid >> 2, chkU = (tid & 3) * 8;
  const int mrow = lane & 15, kq = (lane >> 4) * 8;

  f32x4_t acc[4][8];
#pragma unroll
  for (int i = 0; i < 4; ++i)
#pragma unroll
    for (int j = 0; j < 8; ++j) acc[i][j] = (f32x4_t){0.f, 0.f, 0.f, 0.f};

  for (int kc = 0; kc < F_; kc += 32) {
    gload16(gs + (m0 + rowU) * F_ + kc + chkU, As + rowU * 32 + chkU);
#pragma unroll
    for (int it = 0; it < 4; ++it)
      gload16(ws + (it * 128 + rowU) * F_ + kc + chkU, Bs + (it * 128 + rowU) * 32 + chkU);
    __syncthreads();

    bf16x8_t af[4], bfr[8];
#pragma unroll
    for (int i = 0; i < 4; ++i)
      af[i] = *(const bf16x8_t*)&As[((wr << 6) + i * 16 + mrow) * 32 + kq];
#pragma unroll
    for (int j = 0; j < 8; ++j)
      bfr[j] = *(const bf16x8_t*)&Bs[((wcol << 7) + j * 16 + mrow) * 32 + kq];

#pragma unroll
    for (int i = 0; i < 4; ++i)
#pragma unroll
      for (int j = 0; j < 8; ++j)
        acc[i][j] = __builtin_amdgcn_mfma_f32_16x16x32_bf16(af[i], bfr[j], acc[i][j], 0, 0, 0);
    __syncthreads();
  }

  // epilogue: relu -> bf16, in-place
  const int rbase = (lane >> 4) << 2;
#pragma unroll
  for (int i = 0; i < 4; ++i)
#pragma unroll
    for (int j = 0; j < 8; ++j)
#pragma unroll
      for (int r = 0; r < 4; ++r) {
        int row = (wr << 6) + i * 16 + rbase + r;
        int col = (wcol << 7) + j * 16 + mrow;
        float v = fmaxf(acc[i][j][r], 0.f);
        gs[(m0 + row) * F_ + col] = (short)__bfloat16_as_ushort(__float2bfloat16(v));
      }
}

// ---------------------------------------------------------------------------
// gemm_feat (MFMA): feat = h2[8192x8192] @ wmT^T -> unnormalized out[b][f][t]
// BM=128, BN=128, in-block split-K: 512 threads, waves 0-3 K[0,4096),
// waves 4-7 K[4096,8192). Merge + transpose via LDS. Grid 256.
// ---------------------------------------------------------------------------
__global__ __launch_bounds__(512, 2) void gemm_feat(
    const __hip_bfloat16* __restrict__ h2g, const __hip_bfloat16* __restrict__ wmTg,
    float* __restrict__ out)
{
  __shared__ __align__(16) char smem[33792];
  short* As0 = (short*)smem;                 // [128][32]
  short* Bs0 = (short*)(smem + 8192);        // [128][32]
  short* As1 = (short*)(smem + 16384);
  short* Bs1 = (short*)(smem + 24576);
  float* sM = (float*)smem;                  // merge [64][132]   (33792 B)
  float* sT = (float*)smem;                  // transpose [128][65] (33280 B)

  const short* h2s  = (const short*)h2g;
  const short* wmTs = (const short*)wmTg;

  const int tid = threadIdx.x;
  const int bx = blockIdx.x;
  const int mt = bx >> 2, nt = bx & 3;
  const long long m0 = (long long)mt * 128;
  const int n0 = nt * 128;

  const int wave8 = tid >> 6;
  const int half = wave8 >> 2;      // K-half
  const int wave = wave8 & 3;
  const int lane = tid & 63;
  const int wr = wave >> 1, wc = wave & 1;
  const int mrow = lane & 15;
  const int kq = (lane >> 4) * 8;

  const short* aBase = h2s + m0 * K_TOT;
  const short* bBase = wmTs + (long long)n0 * K_TOT;

  const int rowU = tid >> 2, chkU = (tid & 3) * 8;

  f32x4_t acc[4][4];
#pragma unroll
  for (int i = 0; i < 4; ++i)
#pragma unroll
    for (int j = 0; j < 4; ++j) acc[i][j] = (f32x4_t){0.f, 0.f, 0.f, 0.f};

  short* AsH = half ? As1 : As0;
  short* BsH = half ? Bs1 : Bs0;

  for (int ks = 0; ks < 4096; ks += 32) {
    gload16(aBase + (long long)rowU * K_TOT + ks + chkU,        As0 + rowU * 32 + chkU);
    gload16(bBase + (long long)rowU * K_TOT + ks + chkU,        Bs0 + rowU * 32 + chkU);
    gload16(aBase + (long long)rowU * K_TOT + 4096 + ks + chkU, As1 + rowU * 32 + chkU);
    gload16(bBase + (long long)rowU * K_TOT + 4096 + ks + chkU, Bs1 + rowU * 32 + chkU);
    __syncthreads();

    bf16x8_t af[4], bfr[4];
#pragma unroll
    for (int i = 0; i < 4; ++i)
      af[i] = *(const bf16x8_t*)&AsH[((wr << 6) + i * 16 + mrow) * 32 + kq];
#pragma unroll
    for (int j = 0; j < 4; ++j)
      bfr[j] = *(const bf16x8_t*)&BsH[((wc << 6) + j * 16 + mrow) * 32 + kq];

#pragma unroll
    for (int i = 0; i < 4; ++i)
#pragma unroll
      for (int j = 0; j < 4; ++j)
        acc[i][j] = __builtin_amdgcn_mfma_f32_16x16x32_bf16(af[i], bfr[j], acc[i][j], 0, 0, 0);
    __syncthreads();
  }

  // merge half-1 accs into half-0 waves (2 row-rounds through LDS, stride 132)
  const int rq = (lane >> 4) << 2;
#pragma unroll
  for (int r = 0; r < 2; ++r) {
    if (half == 1 && wr == r) {
#pragma unroll
      for (int i = 0; i < 4; ++i)
#pragma unroll
        for (int j = 0; j < 4; ++j)
#pragma unroll
          for (int rr = 0; rr < 4; ++rr)
            sM[(i * 16 + rq + rr) * 132 + (wc << 6) + j * 16 + mrow] = acc[i][j][rr];
    }
    __syncthreads();
    if (half == 0 && wr == r) {
#pragma unroll
      for (int i = 0; i < 4; ++i)
#pragma unroll
        for (int j = 0; j < 4; ++j)
#pragma unroll
          for (int rr = 0; rr < 4; ++rr)
            acc[i][j][rr] += sM[(i * 16 + rq + rr) * 132 + (wc << 6) + j * 16 + mrow];
    }
    __syncthreads();
  }

  // epilogue: transpose chunks of 64 cols via LDS, store unnormalized out[b][f][t]
  const int b = (int)(m0 >> 11);
  const int t0 = (int)(m0 & 2047);
#pragma unroll
  for (int cch = 0; cch < 2; ++cch) {
    if (half == 0 && wc == cch) {
#pragma unroll
      for (int i = 0; i < 4; ++i)
#pragma unroll
        for (int j = 0; j < 4; ++j)
#pragma unroll
          for (int rr = 0; rr < 4; ++rr)
            sT[((wr << 6) + i * 16 + rq + rr) * 65 + j * 16 + mrow] = acc[i][j][rr];
    }
    __syncthreads();
    long long ob = (long long)b * (F_ * T_) + (long long)(n0 + cch * 64) * T_ + t0;
    for (int idx = tid; idx < 64 * 128; idx += 512) {
      int f = idx >> 7, m = idx & 127;
      out[ob + (long long)f * T_ + m] = sT[m * 65 + f];
    }
    __syncthreads();
  }
}

// ---------------------------------------------------------------------------
// LN in-place on out[b][f][t]: per (b,t) normalize over f
// ---------------------------------------------------------------------------
__global__ __launch_bounds__(256) void ln_inplace(
    float* __restrict__ out, const float* __restrict__ lnw, const float* __restrict__ lnb)
{
  __shared__ float sF[F_ * 17];
  __shared__ float red[512];
  __shared__ float smu[16], srstd[16];

  const int tid = threadIdx.x;
  const int p0 = blockIdx.x << 4;
  const int b = p0 >> 11, t0 = p0 & 2047;
  long long ob = (long long)b * (F_ * T_) + t0;

  for (int idx = tid; idx < F_ * 16; idx += 256) {
    int f = idx >> 4, m = idx & 15;
    sF[f * 17 + m] = out[ob + (long long)f * T_ + m];
  }
  __syncthreads();

  {
    int m = tid & 15, s = tid >> 4;
    float sum = 0.f, sq = 0.f;
    for (int f = s; f < F_; f += 16) {
      float v = sF[f * 17 + m];
      sum += v; sq += v * v;
    }
    red[tid] = sum;
    red[256 + tid] = sq;
  }
  __syncthreads();
  if (tid < 16) {
    float sum = 0.f, sq = 0.f;
#pragma unroll
    for (int s = 0; s < 16; ++s) { sum += red[s * 16 + tid]; sq += red[256 + s * 16 + tid]; }
    float mu = sum * (1.f / F_);
    float var = sq * (1.f / F_) - mu * mu;
    smu[tid] = mu;
    srstd[tid] = rsqrtf(var + LN_EPS);
  }
  __syncthreads();

  for (int idx = tid; idx < F_ * 16; idx += 256) {
    int f = idx >> 4, m = idx & 15;
    float v = (sF[f * 17 + m] - smu[m]) * srstd[m] * lnw[f] + lnb[f];
    out[ob + (long long)f * T_ + m] = v;
  }
}

// ---------------------------------------------------------------------------
extern "C" void kernel_launch(void* const* d_in, const int* in_sizes, int n_in,
                              void* d_out, int out_size, void* d_ws, size_t ws_size,
                              hipStream_t stream)
{
  const float* bbox      = (const float*)d_in[0];
  const int*   cls       = (const int*)d_in[1];
  const float* edge      = (const float*)d_in[2];
  const float* W_lin     = (const float*)d_in[3];
  const float* emb_table = (const float*)d_in[4];
  const float* W1        = (const float*)d_in[5];
  const float* W2        = (const float*)d_in[6];
  const float* Wm        = (const float*)d_in[7];
  const float* lnw       = (const float*)d_in[8];
  const float* lnb       = (const float*)d_in[9];
  float* out = (float*)d_out;

  // workspace carve-up (~142.8 MB, <= proven footprint)
  float* emb1 = (float*)d_ws;
  float* wbox = emb1 + EMB1_N;
  __hip_bfloat16* w2bf = (__hip_bfloat16*)(wbox + WBOX_N);
  __hip_bfloat16* wmT  = w2bf + W2BF_N;
  __hip_bfloat16* gbuf = wmT + WMT_N;   // g, then h2 in-place

  precompute_small<<<(EMB1_N + WBOX_N + W2BF_N) / 256, 256, 0, stream>>>(
      emb_table, W1, W_lin, W2, emb1, wbox, w2bf);
  precompute_wmT<<<WMT_N / 256, 256, 0, stream>>>(Wm, wmT);
  k_h1g<<<B_ * T_, 256, 0, stream>>>(bbox, cls, edge, emb1, wbox, gbuf);
  gemm_h2<<<B_ * T_ * N_ / 128, 512, 0, stream>>>(gbuf, w2bf);
  gemm_feat<<<256, 512, 0, stream>>>(gbuf, wmT, out);
  ln_inplace<<<B_ * T_ / 16, 256, 0, stream>>>(out, lnw, lnb);
}